// Round 3
// baseline (188.628 us; speedup 1.0000x reference)
//
#include <hip/hip_runtime.h>

typedef _Float16 half8_t __attribute__((ext_vector_type(8)));
typedef _Float16 half4_t __attribute__((ext_vector_type(4)));
typedef __fp16   fp16x2  __attribute__((ext_vector_type(2)));
typedef float    f32x4  __attribute__((ext_vector_type(4)));

#define MFMA32(a, b, c) __builtin_amdgcn_mfma_f32_16x16x32_f16((a), (b), (c), 0, 0, 0)
#define MFMA16(a, b, c) __builtin_amdgcn_mfma_f32_16x16x16f16((a), (b), (c), 0, 0, 0)

// async global->LDS DMA: LDS dst = wave-uniform base + lane*width (HW rule);
// global src carries the per-lane offset explicitly.
__device__ __forceinline__ void load_lds16(const void* g, void* l) {
    __builtin_amdgcn_global_load_lds(
        (const __attribute__((address_space(1))) unsigned int*)g,
        (__attribute__((address_space(3))) unsigned int*)l, 16, 0, 0);
}
__device__ __forceinline__ void load_lds4(const void* g, void* l) {
    __builtin_amdgcn_global_load_lds(
        (const __attribute__((address_space(1))) unsigned int*)g,
        (__attribute__((address_space(3))) unsigned int*)l, 4, 0, 0);
}

// 4x f32 -> half4 via 2x v_cvt_pkrtz_f16_f32 (bit-cast the __fp16x2 result)
__device__ __forceinline__ half4_t pk4(f32x4 v) {
    fp16x2 lo = __builtin_amdgcn_cvt_pkrtz(v[0], v[1]);
    fp16x2 hi = __builtin_amdgcn_cvt_pkrtz(v[2], v[3]);
    half4_t r;
    r[0] = (_Float16)lo[0]; r[1] = (_Float16)lo[1];
    r[2] = (_Float16)hi[0]; r[3] = (_Float16)hi[1];
    return r;
}

// ---------------------------------------------------------------------------
// Kernel 1: UGRNN recurrence, operand-swapped MFMA (D^T = W^T X^T), with:
//  - log2e scaling folded into weight frags -> every exp is a bare v_exp_f32
//  - 3 rcp -> 1 rcp(A*B*C) + muls (trans ops per element: 6 -> 4)
//  - v_cvt_pkrtz for f32->f16 fragment packing
//  - TWO pairs per block: input staged via 5 global_load_lds DMA instrs/pair;
//    pair-1 DMA issued before pair-0's register-only step loop (latency hidden)
// Layouts as verified in R1: B frag [k=4q+i][n=t16] == C/D layout [4q+r][t16].
// ---------------------------------------------------------------------------
__global__
__attribute__((amdgpu_flat_work_group_size(256, 256)))
void ugrnn_mfma(
    const float* __restrict__ inputs,
    const float* __restrict__ Wn, const float* __restrict__ Wg,
    const float* __restrict__ Ug, const float* __restrict__ bg,
    const float* __restrict__ Wc, const float* __restrict__ Uc,
    const float* __restrict__ bc, const float* __restrict__ We,
    const float* __restrict__ be, _Float16* __restrict__ h_t)
{
    __shared__ float raw[4][2][1088];   // [wave][pair][32 rows * 34 f32]

    const int wave = threadIdx.x >> 6;
    const int lane = threadIdx.x & 63;
    const int t16  = lane & 15;
    const int q    = lane >> 4;

    const int pidx0 = blockIdx.x * 4 + wave;   // [0, 4096)
    const int pidx1 = pidx0 + 4096;            // [4096, 8192)

    const float NL2E = -1.44269504f;   // -log2(e)    : sigmoid arg
    const float TL2E =  2.88539008f;   // 2*log2(e)   : tanh arg

    // weight A-fragments (A[m=t16][k] = W[k][t16]) with scale folding
    half8_t An;
#pragma unroll
    for (int i = 0; i < 8; ++i)
        An[i] = (_Float16)Wn[(q * 8 + i) * 16 + t16];

    half4_t Awg, Aug, Awc, Auc, Awe;
#pragma unroll
    for (int i = 0; i < 4; ++i) {
        const int k = 4 * q + i;
        Awg[i] = (_Float16)(Wg[k * 16 + t16] * NL2E);
        Aug[i] = (_Float16)(Ug[k * 16 + t16] * NL2E);
        Awc[i] = (_Float16)(Wc[k * 16 + t16] * TL2E);
        Auc[i] = (_Float16)(Uc[k * 16 + t16] * TL2E);
        Awe[i] = (_Float16)(We[k * 16 + t16] * TL2E);
    }
    f32x4 bgC, bcC, beC;
#pragma unroll
    for (int r = 0; r < 4; ++r) {
        bgC[r] = bg[4 * q + r] * NL2E;
        bcC[r] = bc[4 * q + r] * TL2E;
        beC[r] = be[4 * q + r] * TL2E;
    }

    const float* g0 = inputs + (size_t)pidx0 * 1088;
    const float* g1 = inputs + (size_t)pidx1 * 1088;
    float* buf0 = &raw[wave][0][0];
    float* buf1 = &raw[wave][1][0];

    f32x4 m0[2], h0a[2], e0a[2], m1[2], h1a[2], e1a[2];
    const f32x4 zc = {0.f, 0.f, 0.f, 0.f};

    auto init_pair = [&](const float* rt, f32x4* m, f32x4* h, f32x4* e) {
#pragma unroll
        for (int u2 = 0; u2 < 2; ++u2) {
            const float* rp = rt + u2 * 544;
            half8_t Bx;                 // B[k=8q+i][n=t16] = neigh[t16][8q+i]
#pragma unroll
            for (int i = 0; i < 8; ++i)
                Bx[i] = (_Float16)rp[t16 * 34 + 1 + q * 8 + i];
            m[u2] = MFMA32(An, Bx, zc);
            const float hv = rp[t16 * 34 + 0];
            const float ev = rp[t16 * 34 + 33];
            h[u2] = (f32x4){hv, hv, hv, hv};
            e[u2] = (f32x4){ev, ev, ev, ev};
        }
    };

    auto run_pair = [&](int pidx, f32x4* m, f32x4* h, f32x4* e) {
#pragma unroll 1
        for (int step = 0; step < 8; ++step) {
            f32x4 gp[2], cp[2], ep[2];
#pragma unroll
            for (int u2 = 0; u2 < 2; ++u2) {
                const f32x4 x = m[u2] + e[u2];
                half4_t xB = pk4(x);
                half4_t hB = pk4(h[u2]);
                gp[u2] = MFMA16(Aug, hB, MFMA16(Awg, xB, bgC));
                cp[u2] = MFMA16(Auc, hB, MFMA16(Awc, xB, bcC));
                if (step < 7) ep[u2] = MFMA16(Awe, xB, beC);
            }
#pragma unroll
            for (int u2 = 0; u2 < 2; ++u2) {
#pragma unroll
                for (int r = 0; r < 4; ++r) {
                    const float Ae = 1.0f + __builtin_amdgcn_exp2f(gp[u2][r]);
                    const float Be = 1.0f + __builtin_amdgcn_exp2f(cp[u2][r]);
                    if (step < 7) {
                        const float Ce = 1.0f + __builtin_amdgcn_exp2f(ep[u2][r]);
                        const float BC = Be * Ce;
                        const float rr = __builtin_amdgcn_rcpf(Ae * BC);
                        const float gv = rr * BC;              // sigma(gate)
                        const float rb = rr * (Ae * Ce);       // 1/Be
                        const float rc = rr * (Ae * Be);       // 1/Ce
                        const float cv = 1.0f - 2.0f * rb;     // tanh(c)
                        h[u2][r] = cv + gv * (h[u2][r] - cv);
                        e[u2][r] = 1.0f - 2.0f * rc;           // tanh(e)
                    } else {
                        const float rr = __builtin_amdgcn_rcpf(Ae * Be);
                        const float gv = rr * Be;
                        const float cv = 1.0f - 2.0f * (rr * Ae);
                        h[u2][r] = cv + gv * (h[u2][r] - cv);
                    }
                }
            }
        }
        const int b  = pidx >> 7;
        const int n0 = (pidx & 127) << 5;
#pragma unroll
        for (int u2 = 0; u2 < 2; ++u2)
            *(half4_t*)(h_t + (size_t)b * 65536
                            + (size_t)(n0 + u2 * 16 + t16) * 16 + 4 * q) =
                pk4(h[u2]);
    };

    // DMA pair 0 (5 instr, 4352 B), wait, extract frags
#pragma unroll
    for (int k2 = 0; k2 < 4; ++k2)
        load_lds16(g0 + k2 * 256 + lane * 4, buf0 + k2 * 256);
    load_lds4(g0 + 1024 + lane, buf0 + 1024);
    asm volatile("s_waitcnt vmcnt(0)" ::: "memory");
    __builtin_amdgcn_sched_barrier(0);
    init_pair(buf0, m0, h0a, e0a);

    // DMA pair 1 — flies under pair 0's register-only step loop
#pragma unroll
    for (int k2 = 0; k2 < 4; ++k2)
        load_lds16(g1 + k2 * 256 + lane * 4, buf1 + k2 * 256);
    load_lds4(g1 + 1024 + lane, buf1 + 1024);

    run_pair(pidx0, m0, h0a, e0a);

    asm volatile("s_waitcnt vmcnt(0)" ::: "memory");
    __builtin_amdgcn_sched_barrier(0);
    init_pair(buf1, m1, h1a, e1a);
    run_pair(pidx1, m1, h1a, e1a);
}

// ---------------------------------------------------------------------------
// Kernel 2: FC1 partial GEMM, DMA-pipelined, widened to 8 waves/block.
// Per-wave work halves (2 j-tiles instead of 4); more waves overlap the
// per-chunk DMA drain. Same 132 KB double-buffered LDS, 1 block/CU.
// ---------------------------------------------------------------------------
__global__
__attribute__((amdgpu_flat_work_group_size(512, 512), amdgpu_waves_per_eu(1, 2)))
void fc1_mfma(const _Float16* __restrict__ h_t, const float* __restrict__ W1,
              _Float16* __restrict__ partials)
{
    __shared__ float w1s[2][64][258];         // 132096 B
    const int tid  = threadIdx.x;
    const int wave = tid >> 6;                // 0..7
    const int lane = tid & 63;
    const int t16  = lane & 15;
    const int q    = lane >> 4;
    const int i0   = blockIdx.x * 256;

    f32x4 acc[4][2];
#pragma unroll
    for (int mt = 0; mt < 4; ++mt)
#pragma unroll
        for (int nt = 0; nt < 2; ++nt)
            acc[mt][nt] = (f32x4){0.f, 0.f, 0.f, 0.f};

    // prologue: DMA chunk 0 (each wave stages 8 rows; 1 KB per instr)
#pragma unroll
    for (int r = 0; r < 8; ++r) {
        int row = wave * 8 + r;
        load_lds16(W1 + (size_t)(i0 + row) * 256 + lane * 4, &w1s[0][row][0]);
    }
    __syncthreads();                           // drains chunk-0 DMA

#pragma unroll 1
    for (int c = 0; c < 4; ++c) {
        const int buf = c & 1;
        const int cb  = i0 + c * 64;

        // A-frags issued BEFORE next DMA so their vmcnt wait does not drain
        // the DMA queue
        half8_t A[2][4];
#pragma unroll
        for (int ks = 0; ks < 2; ++ks)
#pragma unroll
            for (int mt = 0; mt < 4; ++mt)
                A[ks][mt] = *(const half8_t*)(h_t
                    + (size_t)(mt * 16 + t16) * 65536 + cb + ks * 32 + q * 8);

        if (c < 3) {
#pragma unroll
            for (int r = 0; r < 8; ++r) {
                int row = wave * 8 + r;
                load_lds16(W1 + (size_t)(cb + 64 + row) * 256 + lane * 4,
                           &w1s[buf ^ 1][row][0]);
            }
        }

#pragma unroll
        for (int ks = 0; ks < 2; ++ks) {
#pragma unroll
            for (int nt = 0; nt < 2; ++nt) {
                int j = (wave * 2 + nt) * 16 + t16;
                half8_t Bf;
#pragma unroll
                for (int i = 0; i < 8; ++i)
                    Bf[i] = (_Float16)w1s[buf][ks * 32 + q * 8 + i][j];
#pragma unroll
                for (int mt = 0; mt < 4; ++mt)
                    acc[mt][nt] = MFMA32(A[ks][mt], Bf, acc[mt][nt]);
            }
        }
        __syncthreads();                       // sync + drain next-chunk DMA
    }

    _Float16* pb = partials + (size_t)blockIdx.x * 16384;
#pragma unroll
    for (int mt = 0; mt < 4; ++mt)
#pragma unroll
        for (int nt = 0; nt < 2; ++nt)
#pragma unroll
            for (int r = 0; r < 4; ++r)
                pb[(mt * 16 + 4 * q + r) * 256 + (wave * 2 + nt) * 16 + t16] =
                    (_Float16)acc[mt][nt][r];
}

// ---------------------------------------------------------------------------
// Kernel 3: fused partial-reduce + bias + tail MLP + softmax.
// Phase-1 restructured: 16 K-groups x half4 vector loads (512 B/instr
// coalesced, 16-deep chain instead of 64-deep scalar).
// ---------------------------------------------------------------------------
__global__ __launch_bounds__(1024) void mlp_tail(
    const _Float16* __restrict__ partials, const float* __restrict__ b1,
    const float* __restrict__ W2, const float* __restrict__ b2,
    const float* __restrict__ W3, const float* __restrict__ b3,
    float* __restrict__ out)
{
    __shared__ float x1p[16][256];
    __shared__ float x1s[256];
    __shared__ float x2q[32][33];
    __shared__ float x2s[32];
    __shared__ float lg[2];
    const int b = blockIdx.x, tid = threadIdx.x;
    const int kg = tid >> 6, l64 = tid & 63;
    const int j0 = l64 * 4;

    const _Float16* p = partials + (size_t)(kg * 16) * 16384 + (size_t)b * 256 + j0;
    float s0 = 0.f, s1 = 0.f, s2 = 0.f, s3 = 0.f;
#pragma unroll
    for (int k = 0; k < 16; ++k) {
        half4_t v = *(const half4_t*)(p + (size_t)k * 16384);
        s0 += (float)v[0]; s1 += (float)v[1]; s2 += (float)v[2]; s3 += (float)v[3];
    }
    x1p[kg][j0 + 0] = s0;
    x1p[kg][j0 + 1] = s1;
    x1p[kg][j0 + 2] = s2;
    x1p[kg][j0 + 3] = s3;
    __syncthreads();

    if (tid < 256) {
        float t = b1[tid];
#pragma unroll
        for (int g = 0; g < 16; ++g) t += x1p[g][tid];
        x1s[tid] = fmaxf(t, 0.f);
    }
    __syncthreads();

    const int j2 = tid & 31, g2 = tid >> 5;
    float s = 0.f;
#pragma unroll
    for (int k = g2 * 8; k < g2 * 8 + 8; ++k) s += x1s[k] * W2[k * 32 + j2];
    x2q[g2][j2] = s;
    __syncthreads();
    if (tid < 32) {
        float t = b2[tid];
#pragma unroll
        for (int g = 0; g < 32; ++g) t += x2q[g][tid];
        x2s[tid] = fmaxf(t, 0.f);
    }
    __syncthreads();
    if (tid < 2) {
        float t = b3[tid];
#pragma unroll
        for (int k = 0; k < 32; ++k) t += x2s[k] * W3[k * 2 + tid];
        lg[tid] = t;
    }
    __syncthreads();
    if (tid == 0) {
        float mx = fmaxf(lg[0], lg[1]);
        float e0 = __expf(lg[0] - mx), e1 = __expf(lg[1] - mx);
        float inv = 1.0f / (e0 + e1);
        out[b * 2 + 0] = e0 * inv;
        out[b * 2 + 1] = e1 * inv;
    }
}

// ---------------------------------------------------------------------------
extern "C" void kernel_launch(void* const* d_in, const int* in_sizes, int n_in,
                              void* d_out, int out_size, void* d_ws, size_t ws_size,
                              hipStream_t stream) {
    const float* inputs = (const float*)d_in[0];
    const float* Wn = (const float*)d_in[1];
    const float* Wg = (const float*)d_in[2];
    const float* Ug = (const float*)d_in[3];
    const float* bg = (const float*)d_in[4];
    const float* Wc = (const float*)d_in[5];
    const float* Uc = (const float*)d_in[6];
    const float* bc = (const float*)d_in[7];
    const float* We = (const float*)d_in[8];
    const float* be = (const float*)d_in[9];
    const float* W1 = (const float*)d_in[10];
    const float* b1 = (const float*)d_in[11];
    const float* W2 = (const float*)d_in[12];
    const float* b2 = (const float*)d_in[13];
    const float* W3 = (const float*)d_in[14];
    const float* b3 = (const float*)d_in[15];
    float* out = (float*)d_out;

    // ws: h_t f16 [64][65536] = 8 MB; partials f16 [256][64][256] = 8 MB
    _Float16* h_t      = (_Float16*)d_ws;
    _Float16* partials = (_Float16*)((char*)d_ws + (size_t)64 * 65536 * 2);

    ugrnn_mfma<<<1024, 256, 0, stream>>>(inputs, Wn, Wg, Ug, bg, Wc, Uc, bc,
                                         We, be, h_t);
    fc1_mfma<<<256, 512, 0, stream>>>(h_t, W1, partials);
    mlp_tail<<<64, 1024, 0, stream>>>(partials, b1, W2, b2, W3, b3, out);
}

// Round 4
// 184.644 us; speedup vs baseline: 1.0216x; 1.0216x over previous
//
#include <hip/hip_runtime.h>

typedef _Float16 half8_t __attribute__((ext_vector_type(8)));
typedef _Float16 half4_t __attribute__((ext_vector_type(4)));
typedef __fp16   fp16x2  __attribute__((ext_vector_type(2)));
typedef float    f32x4  __attribute__((ext_vector_type(4)));

#define MFMA32(a, b, c) __builtin_amdgcn_mfma_f32_16x16x32_f16((a), (b), (c), 0, 0, 0)
#define MFMA16(a, b, c) __builtin_amdgcn_mfma_f32_16x16x16f16((a), (b), (c), 0, 0, 0)

// async global->LDS DMA: LDS dst = wave-uniform base + lane*width (HW rule);
// global src carries the per-lane offset explicitly.
__device__ __forceinline__ void load_lds16(const void* g, void* l) {
    __builtin_amdgcn_global_load_lds(
        (const __attribute__((address_space(1))) unsigned int*)g,
        (__attribute__((address_space(3))) unsigned int*)l, 16, 0, 0);
}
__device__ __forceinline__ void load_lds4(const void* g, void* l) {
    __builtin_amdgcn_global_load_lds(
        (const __attribute__((address_space(1))) unsigned int*)g,
        (__attribute__((address_space(3))) unsigned int*)l, 4, 0, 0);
}

// 4x f32 -> half4 via 2x v_cvt_pkrtz_f16_f32 (bit-cast the __fp16x2 result)
__device__ __forceinline__ half4_t pk4(f32x4 v) {
    fp16x2 lo = __builtin_amdgcn_cvt_pkrtz(v[0], v[1]);
    fp16x2 hi = __builtin_amdgcn_cvt_pkrtz(v[2], v[3]);
    half4_t r;
    r[0] = (_Float16)lo[0]; r[1] = (_Float16)lo[1];
    r[2] = (_Float16)hi[0]; r[3] = (_Float16)hi[1];
    return r;
}

// ---------------------------------------------------------------------------
// Kernel 1: UGRNN recurrence, operand-swapped MFMA (D^T = W^T X^T).
// R4: REVERT to R1 single-pair-per-wave structure (grid 2048 -> 32 waves/CU,
// low VGPR) -- R3's two-pair version halved TLP and regressed. KEEP the math:
//  - log2e folded into weight frags -> bare v_exp_f32 (exp2)
//  - one rcp for 3 sigmoids: rcp(A*B*C) + muls (4 trans/elem instead of 6)
//  - v_cvt_pkrtz packing; 5-instr global_load_lds input staging.
// Layouts (verified R1): B frag [k=4q+i][n=t16] == C/D layout [4q+r][t16],
// so each step's f32 state feeds the next MFMA with zero LDS traffic.
// ---------------------------------------------------------------------------
__global__
__attribute__((amdgpu_flat_work_group_size(256, 256)))
void ugrnn_mfma(
    const float* __restrict__ inputs,
    const float* __restrict__ Wn, const float* __restrict__ Wg,
    const float* __restrict__ Ug, const float* __restrict__ bg,
    const float* __restrict__ Wc, const float* __restrict__ Uc,
    const float* __restrict__ bc, const float* __restrict__ We,
    const float* __restrict__ be, _Float16* __restrict__ h_t)
{
    __shared__ float raw[4][1088];      // [wave][32 rows * 34 f32]

    const int wave = threadIdx.x >> 6;
    const int lane = threadIdx.x & 63;
    const int t16  = lane & 15;
    const int q    = lane >> 4;

    const int pair = blockIdx.x * 4 + wave;    // [0, 8192)
    const int b    = pair >> 7;
    const int n0   = (pair & 127) << 5;

    // stage this wave's 32 input rows via 5 DMA instrs (4.3 KB)
    const float* gsrc = inputs + (size_t)pair * 1088;
    float* buf = raw[wave];
#pragma unroll
    for (int k2 = 0; k2 < 4; ++k2)
        load_lds16(gsrc + k2 * 256 + lane * 4, buf + k2 * 256);
    load_lds4(gsrc + 1024 + lane, buf + 1024);

    const float NL2E = -1.44269504f;   // -log2(e)   : sigmoid arg scale
    const float TL2E =  2.88539008f;   // 2*log2(e)  : tanh arg scale

    // weight A-fragments (A[m=t16][k] = W[k][t16]); these global loads fly
    // concurrently with the DMA above
    half8_t An;
#pragma unroll
    for (int i = 0; i < 8; ++i)
        An[i] = (_Float16)Wn[(q * 8 + i) * 16 + t16];

    half4_t Awg, Aug, Awc, Auc, Awe;
#pragma unroll
    for (int i = 0; i < 4; ++i) {
        const int k = 4 * q + i;
        Awg[i] = (_Float16)(Wg[k * 16 + t16] * NL2E);
        Aug[i] = (_Float16)(Ug[k * 16 + t16] * NL2E);
        Awc[i] = (_Float16)(Wc[k * 16 + t16] * TL2E);
        Auc[i] = (_Float16)(Uc[k * 16 + t16] * TL2E);
        Awe[i] = (_Float16)(We[k * 16 + t16] * TL2E);
    }
    f32x4 bgC, bcC, beC;
#pragma unroll
    for (int r = 0; r < 4; ++r) {
        bgC[r] = bg[4 * q + r] * NL2E;
        bcC[r] = bc[4 * q + r] * TL2E;
        beC[r] = be[4 * q + r] * TL2E;
    }

    asm volatile("s_waitcnt vmcnt(0)" ::: "memory");
    __builtin_amdgcn_sched_barrier(0);

    f32x4 m[2], h[2], e[2];
    const f32x4 zc = {0.f, 0.f, 0.f, 0.f};
#pragma unroll
    for (int u2 = 0; u2 < 2; ++u2) {
        const float* rp = buf + u2 * 544;
        half8_t Bx;                     // B[k=8q+i][n=t16] = neigh[t16][8q+i]
#pragma unroll
        for (int i = 0; i < 8; ++i)
            Bx[i] = (_Float16)rp[t16 * 34 + 1 + q * 8 + i];
        m[u2] = MFMA32(An, Bx, zc);
        const float hv = rp[t16 * 34 + 0];
        const float ev = rp[t16 * 34 + 33];
        h[u2] = (f32x4){hv, hv, hv, hv};
        e[u2] = (f32x4){ev, ev, ev, ev};
    }

#pragma unroll 1
    for (int step = 0; step < 8; ++step) {
        f32x4 gp[2], cp[2], ep[2];
#pragma unroll
        for (int u2 = 0; u2 < 2; ++u2) {
            const f32x4 x = m[u2] + e[u2];
            half4_t xB = pk4(x);
            half4_t hB = pk4(h[u2]);
            gp[u2] = MFMA16(Aug, hB, MFMA16(Awg, xB, bgC));
            cp[u2] = MFMA16(Auc, hB, MFMA16(Awc, xB, bcC));
            if (step < 7) ep[u2] = MFMA16(Awe, xB, beC);
        }
#pragma unroll
        for (int u2 = 0; u2 < 2; ++u2) {
#pragma unroll
            for (int r = 0; r < 4; ++r) {
                const float Ae = 1.0f + __builtin_amdgcn_exp2f(gp[u2][r]);
                const float Be = 1.0f + __builtin_amdgcn_exp2f(cp[u2][r]);
                if (step < 7) {
                    const float Ce = 1.0f + __builtin_amdgcn_exp2f(ep[u2][r]);
                    const float BC = Be * Ce;
                    const float rr = __builtin_amdgcn_rcpf(Ae * BC);
                    const float gv = rr * BC;              // sigma(gate)
                    const float rb = rr * (Ae * Ce);       // 1/Be
                    const float rc = rr * (Ae * Be);       // 1/Ce
                    const float cv = 1.0f - 2.0f * rb;     // tanh(c)
                    h[u2][r] = cv + gv * (h[u2][r] - cv);
                    e[u2][r] = 1.0f - 2.0f * rc;           // tanh(e)
                } else {
                    const float rr = __builtin_amdgcn_rcpf(Ae * Be);
                    const float gv = rr * Be;
                    const float cv = 1.0f - 2.0f * (rr * Ae);
                    h[u2][r] = cv + gv * (h[u2][r] - cv);
                }
            }
        }
    }

    // coalesced store: 64 lanes tile 512 B contiguously per u2
#pragma unroll
    for (int u2 = 0; u2 < 2; ++u2)
        *(half4_t*)(h_t + (size_t)b * 65536
                        + (size_t)(n0 + u2 * 16 + t16) * 16 + 4 * q) =
            pk4(h[u2]);
}

// ---------------------------------------------------------------------------
// Kernel 2: FC1 partial GEMM. R4: grid 512 (K=128/block), 32-row chunks,
// double-buffered 66 KB LDS -> 2 blocks/CU, so one block's barrier-drain
// overlaps the other's DMA/compute. W1 (64 MB f32) is the BW floor (~10 us).
// ---------------------------------------------------------------------------
__global__
__attribute__((amdgpu_flat_work_group_size(256, 256)))
void fc1_mfma(const _Float16* __restrict__ h_t, const float* __restrict__ W1,
              _Float16* __restrict__ partials)
{
    __shared__ float w1s[2][32][258];          // 66048 B -> 2 blocks/CU
    const int tid  = threadIdx.x;
    const int wave = tid >> 6;                 // 0..3
    const int lane = tid & 63;
    const int t16  = lane & 15;
    const int q    = lane >> 4;
    const int i0   = blockIdx.x * 128;

    f32x4 acc[4][4];
#pragma unroll
    for (int mt = 0; mt < 4; ++mt)
#pragma unroll
        for (int nt = 0; nt < 4; ++nt)
            acc[mt][nt] = (f32x4){0.f, 0.f, 0.f, 0.f};

    // prologue: DMA chunk 0 (each wave stages 8 rows of 1 KB)
#pragma unroll
    for (int r = 0; r < 8; ++r) {
        int row = wave * 8 + r;
        load_lds16(W1 + (size_t)(i0 + row) * 256 + lane * 4, &w1s[0][row][0]);
    }
    __syncthreads();                           // drains chunk-0 DMA

#pragma unroll 1
    for (int c = 0; c < 4; ++c) {
        const int buf = c & 1;
        const int cb  = i0 + c * 32;

        // A-frags issued first so their latency overlaps the DMA
        half8_t A[4];
#pragma unroll
        for (int mt = 0; mt < 4; ++mt)
            A[mt] = *(const half8_t*)(h_t
                + (size_t)(mt * 16 + t16) * 65536 + cb + q * 8);

        if (c < 3) {
#pragma unroll
            for (int r = 0; r < 8; ++r) {
                int row = wave * 8 + r;
                load_lds16(W1 + (size_t)(cb + 32 + row) * 256 + lane * 4,
                           &w1s[buf ^ 1][row][0]);
            }
        }

#pragma unroll
        for (int nt = 0; nt < 4; ++nt) {
            int j = (wave * 4 + nt) * 16 + t16;
            half8_t Bf;
#pragma unroll
            for (int i = 0; i < 8; ++i)
                Bf[i] = (_Float16)w1s[buf][q * 8 + i][j];
#pragma unroll
            for (int mt = 0; mt < 4; ++mt)
                acc[mt][nt] = MFMA32(A[mt], Bf, acc[mt][nt]);
        }
        __syncthreads();                       // sync + drain next-chunk DMA
    }

    _Float16* pb = partials + (size_t)blockIdx.x * 16384;
#pragma unroll
    for (int mt = 0; mt < 4; ++mt)
#pragma unroll
        for (int nt = 0; nt < 4; ++nt)
#pragma unroll
            for (int r = 0; r < 4; ++r)
                pb[(mt * 16 + 4 * q + r) * 256 + (wave * 4 + nt) * 16 + t16] =
                    (_Float16)acc[mt][nt][r];
}

// ---------------------------------------------------------------------------
// Kernel 3: fused partial-reduce + bias + tail MLP + softmax.
// 512 partials now: 16 K-groups x 32 coalesced half4 loads each.
// ---------------------------------------------------------------------------
__global__ __launch_bounds__(1024) void mlp_tail(
    const _Float16* __restrict__ partials, const float* __restrict__ b1,
    const float* __restrict__ W2, const float* __restrict__ b2,
    const float* __restrict__ W3, const float* __restrict__ b3,
    float* __restrict__ out)
{
    __shared__ float x1p[16][256];
    __shared__ float x1s[256];
    __shared__ float x2q[32][33];
    __shared__ float x2s[32];
    __shared__ float lg[2];
    const int b = blockIdx.x, tid = threadIdx.x;
    const int kg = tid >> 6, l64 = tid & 63;
    const int j0 = l64 * 4;

    const _Float16* p = partials + (size_t)(kg * 32) * 16384 + (size_t)b * 256 + j0;
    float s0 = 0.f, s1 = 0.f, s2 = 0.f, s3 = 0.f;
#pragma unroll
    for (int k = 0; k < 32; ++k) {
        half4_t v = *(const half4_t*)(p + (size_t)k * 16384);
        s0 += (float)v[0]; s1 += (float)v[1]; s2 += (float)v[2]; s3 += (float)v[3];
    }
    x1p[kg][j0 + 0] = s0;
    x1p[kg][j0 + 1] = s1;
    x1p[kg][j0 + 2] = s2;
    x1p[kg][j0 + 3] = s3;
    __syncthreads();

    if (tid < 256) {
        float t = b1[tid];
#pragma unroll
        for (int g = 0; g < 16; ++g) t += x1p[g][tid];
        x1s[tid] = fmaxf(t, 0.f);
    }
    __syncthreads();

    const int j2 = tid & 31, g2 = tid >> 5;
    float s = 0.f;
#pragma unroll
    for (int k = g2 * 8; k < g2 * 8 + 8; ++k) s += x1s[k] * W2[k * 32 + j2];
    x2q[g2][j2] = s;
    __syncthreads();
    if (tid < 32) {
        float t = b2[tid];
#pragma unroll
        for (int g = 0; g < 32; ++g) t += x2q[g][tid];
        x2s[tid] = fmaxf(t, 0.f);
    }
    __syncthreads();
    if (tid < 2) {
        float t = b3[tid];
#pragma unroll
        for (int k = 0; k < 32; ++k) t += x2s[k] * W3[k * 2 + tid];
        lg[tid] = t;
    }
    __syncthreads();
    if (tid == 0) {
        float mx = fmaxf(lg[0], lg[1]);
        float e0 = __expf(lg[0] - mx), e1 = __expf(lg[1] - mx);
        float inv = 1.0f / (e0 + e1);
        out[b * 2 + 0] = e0 * inv;
        out[b * 2 + 1] = e1 * inv;
    }
}

// ---------------------------------------------------------------------------
extern "C" void kernel_launch(void* const* d_in, const int* in_sizes, int n_in,
                              void* d_out, int out_size, void* d_ws, size_t ws_size,
                              hipStream_t stream) {
    const float* inputs = (const float*)d_in[0];
    const float* Wn = (const float*)d_in[1];
    const float* Wg = (const float*)d_in[2];
    const float* Ug = (const float*)d_in[3];
    const float* bg = (const float*)d_in[4];
    const float* Wc = (const float*)d_in[5];
    const float* Uc = (const float*)d_in[6];
    const float* bc = (const float*)d_in[7];
    const float* We = (const float*)d_in[8];
    const float* be = (const float*)d_in[9];
    const float* W1 = (const float*)d_in[10];
    const float* b1 = (const float*)d_in[11];
    const float* W2 = (const float*)d_in[12];
    const float* b2 = (const float*)d_in[13];
    const float* W3 = (const float*)d_in[14];
    const float* b3 = (const float*)d_in[15];
    float* out = (float*)d_out;

    // ws: h_t f16 [64][65536] = 8 MB; partials f16 [512][64][256] = 16 MB
    _Float16* h_t      = (_Float16*)d_ws;
    _Float16* partials = (_Float16*)((char*)d_ws + (size_t)64 * 65536 * 2);

    ugrnn_mfma<<<2048, 256, 0, stream>>>(inputs, Wn, Wg, Ug, bg, Wc, Uc, bc,
                                         We, be, h_t);
    fc1_mfma<<<512, 256, 0, stream>>>(h_t, W1, partials);
    mlp_tail<<<64, 1024, 0, stream>>>(partials, b1, W2, b2, W3, b3, out);
}